// Round 4
// baseline (247.608 us; speedup 1.0000x reference)
//
#include <hip/hip_runtime.h>
#include <stdint.h>

#define KQ    8      // queries per streaming block
#define CAP   256    // survivor capacity per query (expected ~54; validated R2)
#define NCH   4      // point-stream chunks for p1/p2 (gridDim.y)
#define KNB   16

typedef short short8 __attribute__((ext_vector_type(8)));
typedef float floatx4 __attribute__((ext_vector_type(4)));
typedef float floatx2 __attribute__((ext_vector_type(2)));

__device__ __forceinline__ unsigned short f2bf(float x) {
  union { float f; uint32_t u; } v; v.f = x;
  uint32_t u = v.u + 0x7FFFu + ((v.u >> 16) & 1u);   // RNE
  return (unsigned short)(u >> 16);
}
__device__ __forceinline__ float bf2f(unsigned short b) {
  return __uint_as_float(((uint32_t)b) << 16);
}

// order-preserving f32 <-> u32 (for atomicMin on t values)
__device__ __forceinline__ uint32_t fmap(float f) {
  uint32_t b = __float_as_uint(f);
  return (b & 0x80000000u) ? ~b : (b | 0x80000000u);
}
__device__ __forceinline__ float funmap(uint32_t u) {
  return __uint_as_float((u & 0x80000000u) ? (u & 0x7FFFFFFFu) : ~u);
}

static __device__ __forceinline__ floatx2 fma2(floatx2 a, floatx2 b, floatx2 c) {
#if __has_builtin(__builtin_elementwise_fma)
  return __builtin_elementwise_fma(a, b, c);    // -> v_pk_fma_f32
#else
  floatx2 r; r[0] = fmaf(a[0], b[0], c[0]); r[1] = fmaf(a[1], b[1], c[1]);
  return r;
#endif
}
static __device__ __forceinline__ floatx2 min2(floatx2 a, floatx2 b) {
#if __has_builtin(__builtin_elementwise_min)
  return __builtin_elementwise_min(a, b);
#else
  floatx2 r; r[0] = fminf(a[0], b[0]); r[1] = fminf(a[1], b[1]);
  return r;
#endif
}
static __device__ __forceinline__ floatx2 sp2(float v) {
  floatx2 r; r[0] = v; r[1] = v; return r;
}

// ---------------------------------------------------------------------------
// prep: xb = bf16(x); pos4 = {x,y,z,pp}; pospk = pair-SoA with 3e38 sentinel
// pads; Wt = bf16 W^T; gmin_g = 0xFFFFFFFF; cnt_g = 0.
// ---------------------------------------------------------------------------
__global__ void prep_kernel(const float* __restrict__ x,
                            const float* __restrict__ pos,
                            const float* __restrict__ W_att,
                            unsigned short* __restrict__ xb,
                            float4* __restrict__ pos4,
                            float* __restrict__ pospk,
                            unsigned short* __restrict__ Wt,
                            uint32_t* __restrict__ gmin_g,
                            int* __restrict__ cnt_g,
                            int N, int Npad2, int M) {
  int id = blockIdx.x * 256 + threadIdx.x;
  int nx8 = N * 8;
  if (id < nx8) {
    const float4* src = (const float4*)x + (size_t)id * 2;
    float4 a = src[0], b = src[1];
    short8 v;
    v[0] = (short)f2bf(a.x); v[1] = (short)f2bf(a.y);
    v[2] = (short)f2bf(a.z); v[3] = (short)f2bf(a.w);
    v[4] = (short)f2bf(b.x); v[5] = (short)f2bf(b.y);
    v[6] = (short)f2bf(b.z); v[7] = (short)f2bf(b.w);
    *(short8*)(xb + (size_t)id * 8) = v;
  } else if (id < nx8 + Npad2) {
    int j = id - nx8;
    float px = 0.f, py = 0.f, pz = 0.f, pp = 3.0e38f;
    if (j < N) {
      px = pos[3 * j]; py = pos[3 * j + 1]; pz = pos[3 * j + 2];
      pp = fmaf(px, px, fmaf(py, py, pz * pz));
      pos4[j] = make_float4(px, py, pz, pp);
    }
    int pair = j >> 1, h = j & 1;
    float* dst = pospk + (size_t)pair * 8;
    dst[0 + h] = px; dst[2 + h] = py; dst[4 + h] = pz; dst[6 + h] = pp;
  } else if (id < nx8 + Npad2 + 128 * 128) {
    int t = id - nx8 - Npad2;
    int c = t >> 7, f = t & 127;
    Wt[f * 128 + c] = f2bf(W_att[t]);
  } else if (id < nx8 + Npad2 + 128 * 128 + M * 16) {
    gmin_g[id - nx8 - Npad2 - 128 * 128] = 0xFFFFFFFFu;
  } else if (id < nx8 + Npad2 + 128 * 128 + M * 16 + M) {
    cnt_g[id - nx8 - Npad2 - 128 * 128 - M * 16] = 0;
  }
}

// ---------------------------------------------------------------------------
// p1: stream chunk, per-lane packed t-mins, reduce to 16 disjoint group mins,
// atomicMin-merge into gmin_g[m][16]. Groups partition all points (chunk,lane)
// -> tau = max_g min_g >= t_(16) argument unchanged.
// ---------------------------------------------------------------------------
__global__ __launch_bounds__(256) void knn_p1(
    const float4* __restrict__ pos4, const float4* __restrict__ pospk4,
    const int* __restrict__ idx, uint32_t* __restrict__ gmin_g,
    int Npad2, int M) {
  __shared__ float gmin_l[KQ][16];
  const int tid = threadIdx.x;
  const int q0  = blockIdx.x * KQ;
  const int cpts = Npad2 / NCH;            // points per chunk (mult of 512)
  const int c0f4 = blockIdx.y * cpts;      // float4 base (2 float4 per pair)
  const int iters = cpts >> 9;             // 512 points per block-iter

  float sx[KQ], sy[KQ], sz[KQ];
#pragma unroll
  for (int qi = 0; qi < KQ; ++qi) {
    int m = q0 + qi; if (m >= M) m = M - 1;
    float4 qp = pos4[idx[m]];
    sx[qi] = -2.f * qp.x; sy[qi] = -2.f * qp.y; sz[qi] = -2.f * qp.z;
  }

  floatx2 tmn[KQ];
#pragma unroll
  for (int qi = 0; qi < KQ; ++qi) tmn[qi] = sp2(3.4e38f);
  {
    float4 a = pospk4[c0f4 + tid * 2], b = pospk4[c0f4 + tid * 2 + 1];
    for (int it = 0; it < iters; ++it) {
      float4 an = a, bn = b;
      if (it + 1 < iters) {
        int nb = c0f4 + (it + 1) * 512 + tid * 2;
        an = pospk4[nb]; bn = pospk4[nb + 1];
      }
      floatx2 X, Y, Z, W;
      X[0] = a.x; X[1] = a.y; Y[0] = a.z; Y[1] = a.w;
      Z[0] = b.x; Z[1] = b.y; W[0] = b.z; W[1] = b.w;
#pragma unroll
      for (int qi = 0; qi < KQ; ++qi) {
        floatx2 t = fma2(sp2(sx[qi]), X,
                         fma2(sp2(sy[qi]), Y, fma2(sp2(sz[qi]), Z, W)));
        tmn[qi] = min2(tmn[qi], t);
      }
      a = an; b = bn;
    }
  }
#pragma unroll
  for (int qi = 0; qi < KQ; ++qi) {
    float v = fminf(tmn[qi][0], tmn[qi][1]);
    v = fminf(v, __shfl_xor(v, 1));
    v = fminf(v, __shfl_xor(v, 2));
    v = fminf(v, __shfl_xor(v, 4));
    v = fminf(v, __shfl_xor(v, 8));
    if ((tid & 15) == 0) gmin_l[qi][tid >> 4] = v;
  }
  __syncthreads();
  if (tid < 128) {
    int qi = tid >> 4, g = tid & 15;
    int m = q0 + qi; if (m >= M) m = M - 1;   // clamped dup: identical values
    atomicMin(&gmin_g[m * 16 + g], fmap(gmin_l[qi][g]));
  }
}

// ---------------------------------------------------------------------------
// tau finalize: tau[m] = max_g unmap(gmin_g[m][g]) + margin (same margin as
// the passing fused kernel).
// ---------------------------------------------------------------------------
__global__ void knn_tau(const uint32_t* __restrict__ gmin_g,
                        float* __restrict__ tau, int M) {
  int m = blockIdx.x * 256 + threadIdx.x;
  if (m >= M) return;
  uint32_t mx = gmin_g[m * 16];
#pragma unroll
  for (int g = 1; g < 16; ++g) {
    uint32_t u = gmin_g[m * 16 + g];
    mx = (u > mx) ? u : mx;
  }
  float t = funmap(mx);
  tau[m] = t + fabsf(t) * 1e-6f + 1e-7f;
}

// ---------------------------------------------------------------------------
// p2: re-stream chunk, collect survivor indices into global cand via atomic
// slot counter. Invalid (clamped) queries get tau=-inf -> contribute nothing.
// ---------------------------------------------------------------------------
__global__ __launch_bounds__(256) void knn_p2(
    const float4* __restrict__ pos4, const float4* __restrict__ pospk4,
    const int* __restrict__ idx, const float* __restrict__ tau_g,
    int* __restrict__ cnt_g, uint32_t* __restrict__ cand_g,
    int Npad2, int M) {
  const int tid = threadIdx.x;
  const int q0  = blockIdx.x * KQ;
  const int cpts = Npad2 / NCH;
  const int c0f4 = blockIdx.y * cpts;
  const int c0p  = blockIdx.y * cpts;      // chunk base in point units
  const int iters = cpts >> 9;

  float sx[KQ], sy[KQ], sz[KQ], tau[KQ];
  int mcl[KQ];
#pragma unroll
  for (int qi = 0; qi < KQ; ++qi) {
    int m = q0 + qi;
    int mc = (m >= M) ? (M - 1) : m;
    mcl[qi] = mc;
    float4 qp = pos4[idx[mc]];
    sx[qi] = -2.f * qp.x; sy[qi] = -2.f * qp.y; sz[qi] = -2.f * qp.z;
    tau[qi] = (m >= M) ? -3.4e38f : tau_g[mc];
  }

  {
    float4 a = pospk4[c0f4 + tid * 2], b = pospk4[c0f4 + tid * 2 + 1];
    for (int it = 0; it < iters; ++it) {
      float4 an = a, bn = b;
      if (it + 1 < iters) {
        int nb = c0f4 + (it + 1) * 512 + tid * 2;
        an = pospk4[nb]; bn = pospk4[nb + 1];
      }
      floatx2 X, Y, Z, W;
      X[0] = a.x; X[1] = a.y; Y[0] = a.z; Y[1] = a.w;
      Z[0] = b.x; Z[1] = b.y; W[0] = b.z; W[1] = b.w;
      const int j0 = c0p + (it * 256 + tid) * 2;
#pragma unroll
      for (int qi = 0; qi < KQ; ++qi) {
        floatx2 t = fma2(sp2(sx[qi]), X,
                         fma2(sp2(sy[qi]), Y, fma2(sp2(sz[qi]), Z, W)));
        if (fminf(t[0], t[1]) <= tau[qi]) {
          if (t[0] <= tau[qi]) {
            int sl = atomicAdd(&cnt_g[mcl[qi]], 1);
            if (sl < CAP) cand_g[(size_t)mcl[qi] * CAP + sl] = (uint32_t)j0;
          }
          if (t[1] <= tau[qi]) {
            int sl = atomicAdd(&cnt_g[mcl[qi]], 1);
            if (sl < CAP) cand_g[(size_t)mcl[qi] * CAP + sl] = (uint32_t)(j0 + 1);
          }
        }
      }
      a = an; b = bn;
    }
  }
}

// ---------------------------------------------------------------------------
// p3: one wave per query; exact f32 d2 on survivors, extract 16 smallest by
// packed (d2bits<<32|idx) keys -- order-independent, identical to fused ver.
// ---------------------------------------------------------------------------
__global__ __launch_bounds__(256) void knn_p3(
    const float4* __restrict__ pos4, const int* __restrict__ idx,
    const int* __restrict__ cnt_g, const uint32_t* __restrict__ cand_g,
    int* __restrict__ nbr, int M) {
  const int tid = threadIdx.x;
  const int wv = tid >> 6, ln = tid & 63;
  const int m = blockIdx.x * 4 + wv;
  if (m >= M) return;
  int nc = cnt_g[m]; if (nc > CAP) nc = CAP;
  float4 qp = pos4[idx[m]];
  unsigned long long c[CAP / 64];
#pragma unroll
  for (int ch = 0; ch < CAP / 64; ++ch) c[ch] = ~0ull;
#pragma unroll
  for (int ch = 0; ch < CAP / 64; ++ch) {
    int s = ch * 64 + ln;
    if (s < nc) {
      uint32_t j = cand_g[(size_t)m * CAP + s];
      float4 pj = pos4[j];
      float dot = fmaf(qp.x, pj.x, fmaf(qp.y, pj.y, qp.z * pj.z));
      float tt  = fmaf(-2.f, dot, pj.w);
      float d2  = fmaxf(qp.w + tt, 0.f);
      c[ch] = ((unsigned long long)__float_as_uint(d2) << 32) | j;
    }
  }
#pragma unroll
  for (int r = 0; r < KNB; ++r) {
    unsigned long long mn = c[0];
#pragma unroll
    for (int ch = 1; ch < CAP / 64; ++ch) mn = (c[ch] < mn) ? c[ch] : mn;
#pragma unroll
    for (int off = 1; off < 64; off <<= 1) {
      unsigned long long o = __shfl_xor(mn, off);
      mn = (o < mn) ? o : mn;
    }
    if (ln == 0) nbr[m * KNB + r] = (int)(uint32_t)mn;
#pragma unroll
    for (int ch = 0; ch < CAP / 64; ++ch)
      if (c[ch] == mn) c[ch] = ~0ull;
  }
}

// ---------------------------------------------------------------------------
// mid: 8 queries / 256-thread block (unchanged from passing version).
// ---------------------------------------------------------------------------
__global__ __launch_bounds__(256) void mid_kernel(
    const unsigned short* __restrict__ xb, const float4* __restrict__ pos4,
    const int* __restrict__ idx, const float* __restrict__ W_pos,
    const float* __restrict__ b_pos, const unsigned short* __restrict__ Wt,
    const float* __restrict__ b_att, const int* __restrict__ nbr,
    float* __restrict__ aggr, int M) {
  __shared__ __align__(16) unsigned short fijb[8][16][136];
  __shared__ int nbr_s[128];
  __shared__ float4 qpos_s[8];

  const int tid = threadIdx.x;
  const int wid = tid >> 6, lane = tid & 63;
  const int col = lane & 15, quad = lane >> 4;
  const int b = blockIdx.x;

  if (tid < 128) {
    int mq = b * 8 + (tid >> 4); if (mq >= M) mq = M - 1;
    nbr_s[tid] = nbr[mq * 16 + (tid & 15)];
  }
  if (tid < 8) {
    int mq = b * 8 + tid; if (mq >= M) mq = M - 1;
    qpos_s[tid] = pos4[idx[mq]];
  }
  float wp[10];
#pragma unroll
  for (int t = 0; t < 10; ++t) wp[t] = W_pos[t * 64 + lane];
  float bp = b_pos[lane];
  __syncthreads();

  {
    int rr = tid >> 1, h = tid & 1;
    int jn = nbr_s[rr];
    const short8* src = (const short8*)(xb + ((size_t)jn << 6) + (h << 5));
    short8 v0 = src[0], v1 = src[1], v2 = src[2], v3 = src[3];
    short8* dst = (short8*)&fijb[rr >> 4][rr & 15][h * 32];
    dst[0] = v0; dst[1] = v1; dst[2] = v2; dst[3] = v3;
  }
#pragma unroll
  for (int qi = 0; qi < 2; ++qi) {
    int q = wid * 2 + qi;
    float4 qp = qpos_s[q];
#pragma unroll 4
    for (int k = 0; k < 16; ++k) {
      int jn = nbr_s[q * 16 + k];
      float4 pj = pos4[jn];
      float vx = qp.x - pj.x, vy = qp.y - pj.y, vz = qp.z - pj.z;
      float dd = sqrtf(fmaf(vx, vx, fmaf(vy, vy, vz * vz)));
      float r = bp;
      r = fmaf(qp.x, wp[0], r); r = fmaf(qp.y, wp[1], r); r = fmaf(qp.z, wp[2], r);
      r = fmaf(pj.x, wp[3], r); r = fmaf(pj.y, wp[4], r); r = fmaf(pj.z, wp[5], r);
      r = fmaf(vx, wp[6], r);  r = fmaf(vy, wp[7], r);  r = fmaf(vz, wp[8], r);
      r = fmaf(dd, wp[9], r);
      r = fmaxf(r, 0.f);
      fijb[q][k][64 + lane] = f2bf(r);
    }
  }
  __syncthreads();

#pragma unroll 1
  for (int qi = 0; qi < 2; ++qi) {
    int q = wid * 2 + qi;
    int mq = b * 8 + q;

    short8 af[4];
#pragma unroll
    for (int cs = 0; cs < 4; ++cs)
      af[cs] = *(const short8*)&fijb[q][col][cs * 32 + quad * 8];

    floatx4 acc[8];
#pragma unroll
    for (int ft = 0; ft < 8; ++ft) {
      float bav = b_att[ft * 16 + col];
      floatx4 a = {bav, bav, bav, bav};
#pragma unroll
      for (int cs = 0; cs < 4; ++cs) {
        short8 bfrag =
            *(const short8*)&Wt[(ft * 16 + col) * 128 + cs * 32 + quad * 8];
        a = __builtin_amdgcn_mfma_f32_16x16x32_bf16(af[cs], bfrag, a, 0, 0, 0);
      }
      acc[ft] = a;
    }

    float rowmax[4], rowinv[4];
#pragma unroll
    for (int r = 0; r < 4; ++r) {
      float mx = acc[0][r];
#pragma unroll
      for (int ft = 1; ft < 8; ++ft) mx = fmaxf(mx, acc[ft][r]);
      mx = fmaxf(mx, __shfl_xor(mx, 1));
      mx = fmaxf(mx, __shfl_xor(mx, 2));
      mx = fmaxf(mx, __shfl_xor(mx, 4));
      mx = fmaxf(mx, __shfl_xor(mx, 8));
      float sm = 0.f;
#pragma unroll
      for (int ft = 0; ft < 8; ++ft) sm += __expf(acc[ft][r] - mx);
      sm += __shfl_xor(sm, 1);
      sm += __shfl_xor(sm, 2);
      sm += __shfl_xor(sm, 4);
      sm += __shfl_xor(sm, 8);
      rowmax[r] = mx;
      rowinv[r] = 1.0f / sm;
    }

#pragma unroll
    for (int ft = 0; ft < 8; ++ft) {
      float ap = 0.f;
#pragma unroll
      for (int r = 0; r < 4; ++r) {
        float s = __expf(acc[ft][r] - rowmax[r]) * rowinv[r];
        float fv = bf2f(fijb[q][quad * 4 + r][ft * 16 + col]);
        ap = fmaf(s, fv, ap);
      }
      ap += __shfl_xor(ap, 16);
      ap += __shfl_xor(ap, 32);
      if (quad == 0 && mq < M)
        aggr[mq * 128 + ft * 16 + col] = ap * (1.0f / 16.0f);
    }
  }
}

// ---------------------------------------------------------------------------
// out = relu(aggr @ W_glob + b_glob)
// ---------------------------------------------------------------------------
__global__ __launch_bounds__(256) void out_kernel(
    const float* __restrict__ aggr, const float* __restrict__ W_glob,
    const float* __restrict__ b_glob, float* __restrict__ out, int M) {
  __shared__ float ag[16][128];
  const int tid = threadIdx.x;
  const int mbase = blockIdx.x * 16;
  for (int s = tid; s < 16 * 128; s += 256) {
    int r = s >> 7, cc = s & 127;
    int m = mbase + r;
    ((float*)ag)[s] = (m < M) ? aggr[m * 128 + cc] : 0.0f;
  }
  __syncthreads();
  const int f = tid & 127, h = tid >> 7;
  float acc[8];
  float bg = b_glob[f];
#pragma unroll
  for (int i = 0; i < 8; ++i) acc[i] = bg;
  for (int c = 0; c < 128; c += 4) {
    float w0 = W_glob[(c + 0) * 128 + f];
    float w1 = W_glob[(c + 1) * 128 + f];
    float w2 = W_glob[(c + 2) * 128 + f];
    float w3 = W_glob[(c + 3) * 128 + f];
#pragma unroll
    for (int i = 0; i < 8; ++i) {
      const floatx4 a4 = *(const floatx4*)&ag[h * 8 + i][c];
      acc[i] += a4[0] * w0 + a4[1] * w1 + a4[2] * w2 + a4[3] * w3;
    }
  }
#pragma unroll
  for (int i = 0; i < 8; ++i) {
    int m = mbase + h * 8 + i;
    if (m < M) out[m * 128 + f] = fmaxf(acc[i], 0.0f);
  }
}

// ---------------------------------------------------------------------------
extern "C" void kernel_launch(void* const* d_in, const int* in_sizes, int n_in,
                              void* d_out, int out_size, void* d_ws,
                              size_t ws_size, hipStream_t stream) {
  const float* x      = (const float*)d_in[0];
  const float* pos    = (const float*)d_in[1];
  const int*   idx    = (const int*)d_in[2];
  const float* W_pos  = (const float*)d_in[3];
  const float* b_pos  = (const float*)d_in[4];
  const float* W_att  = (const float*)d_in[5];
  const float* b_att  = (const float*)d_in[6];
  const float* W_glob = (const float*)d_in[7];
  const float* b_glob = (const float*)d_in[8];
  float* out = (float*)d_out;

  const int N = in_sizes[1] / 3;
  const int M = in_sizes[2];
  // Npad2 multiple of NCH*512 = 2048 so chunks split evenly
  const int Npad2 = (N + 2047) & ~2047;

  char* ws = (char*)d_ws;
  size_t o = 0;
  float4* pos4 = (float4*)(ws + o);               o += ((size_t)N * 16 + 255) & ~(size_t)255;
  unsigned short* xb = (unsigned short*)(ws + o); o += ((size_t)N * 128 + 255) & ~(size_t)255;
  float* pospk = (float*)(ws + o);                o += ((size_t)Npad2 * 16 + 255) & ~(size_t)255;
  unsigned short* Wt = (unsigned short*)(ws + o); o += (128 * 128 * 2 + 255) & ~(size_t)255;
  int* nbr = (int*)(ws + o);                      o += (((size_t)M * KNB * 4) + 255) & ~(size_t)255;
  uint32_t* gmin_g = (uint32_t*)(ws + o);         o += (((size_t)M * 16 * 4) + 255) & ~(size_t)255;
  float* tau = (float*)(ws + o);                  o += (((size_t)M * 4) + 255) & ~(size_t)255;
  int* cnt_g = (int*)(ws + o);                    o += (((size_t)M * 4) + 255) & ~(size_t)255;
  // cand (p2/p3) and aggr (mid/out) never coexist in time -> alias them
  size_t cand_bytes = (size_t)M * CAP * 4;
  size_t aggr_bytes = (size_t)M * 128 * 4;
  uint32_t* cand_g = (uint32_t*)(ws + o);
  float* aggr = (float*)(ws + o);
  o += ((cand_bytes > aggr_bytes ? cand_bytes : aggr_bytes) + 255) & ~(size_t)255;

  int prep_ids = N * 8 + Npad2 + 128 * 128 + M * 16 + M;
  prep_kernel<<<(prep_ids + 255) / 256, 256, 0, stream>>>(
      x, pos, W_att, xb, pos4, pospk, Wt, gmin_g, cnt_g, N, Npad2, M);

  dim3 sgrid((M + KQ - 1) / KQ, NCH);
  knn_p1<<<sgrid, 256, 0, stream>>>(pos4, (const float4*)pospk, idx, gmin_g,
                                    Npad2, M);
  knn_tau<<<(M + 255) / 256, 256, 0, stream>>>(gmin_g, tau, M);
  knn_p2<<<sgrid, 256, 0, stream>>>(pos4, (const float4*)pospk, idx, tau,
                                    cnt_g, cand_g, Npad2, M);
  knn_p3<<<(M + 3) / 4, 256, 0, stream>>>(pos4, idx, cnt_g, cand_g, nbr, M);

  mid_kernel<<<(M + 7) / 8, 256, 0, stream>>>(xb, pos4, idx, W_pos, b_pos, Wt,
                                              b_att, nbr, aggr, M);
  out_kernel<<<(M + 15) / 16, 256, 0, stream>>>(aggr, W_glob, b_glob, out, M);
}